// Round 19
// baseline (207.413 us; speedup 1.0000x reference)
//
#include <hip/hip_runtime.h>

#define NB 2
#define NP 8192
#define D 64
#define KNN 16
#define NBK 256        // x-buckets per batch
#define KNN_BLOCKS (NB * NP / 4)   // 4096
#define CREC 96        // comb record stride (floats); W block at +32 (64B aligned)

typedef float f16v __attribute__((ext_vector_type(16)));

__device__ __forceinline__ float rl_f(float v, int lane) {
  return __uint_as_float((unsigned)__builtin_amdgcn_readlane((int)__float_as_uint(v), lane));
}

// ---------------- fused weight folding + bucket build (6 blocks) ----------------
__global__ void __launch_bounds__(256)
k_foldbuckets(const float* __restrict__ Wg,   const float* __restrict__ bg,
              const float* __restrict__ Wphi, const float* __restrict__ bphi,
              const float* __restrict__ Wpsi, const float* __restrict__ bpsi,
              const float* __restrict__ Wal,  const float* __restrict__ bal,
              const float* __restrict__ W1,   const float* __restrict__ b1,
              const float* __restrict__ Wd1,  const float* __restrict__ bd1,
              const float* __restrict__ Wd2,  const float* __restrict__ bd2,
              const float* __restrict__ xyz,
              float* __restrict__ Af, float* __restrict__ dAv,
              float* __restrict__ Bf, float* __restrict__ dBv,
              float* __restrict__ Cf, float* __restrict__ dCv,
              float* __restrict__ comb,
              float4* __restrict__ brange, int* __restrict__ bcur)
{
  __shared__ float sT[64 * 65];
  __shared__ float sTb[64];
  __shared__ float4 sWeff[64];
  __shared__ float smn[256], smx[256];
  __shared__ int hcnt[NBK];
  __shared__ float sr[2];
  const int m   = blockIdx.x;
  const int tid = threadIdx.x;

  if (m >= 4) {
    const int b = m - 4;
    float mn = 1e30f, mx = -1e30f;
    for (int i = tid; i < NP; i += 256) {
      float x = xyz[((size_t)b * NP + i) * 3];
      mn = fminf(mn, x); mx = fmaxf(mx, x);
    }
    smn[tid] = mn; smx[tid] = mx; __syncthreads();
    for (int off = 128; off >= 1; off >>= 1) {
      if (tid < off) {
        smn[tid] = fminf(smn[tid], smn[tid+off]);
        smx[tid] = fmaxf(smx[tid], smx[tid+off]);
      }
      __syncthreads();
    }
    if (tid == 0) {
      float xmin = smn[0], xmax = smx[0];
      float wdt = fmaxf((xmax - xmin) / (float)NBK, 1e-20f);
      brange[b] = make_float4(xmin, 1.0f / wdt, wdt, 0.f);
      sr[0] = xmin; sr[1] = 1.0f / wdt;
    }
    hcnt[tid] = 0;
    __syncthreads();

    const float xmin = sr[0], inv = sr[1];
    for (int i = tid; i < NP; i += 256) {
      float x = xyz[((size_t)b * NP + i) * 3];
      int k = min(max((int)((x - xmin) * inv), 0), NBK - 1);
      atomicAdd(&hcnt[k], 1);
    }
    __syncthreads();

    int v = hcnt[tid];
    int acc = v;
    for (int off = 1; off < NBK; off <<= 1) {
      int t = (tid >= off) ? hcnt[tid - off] : 0;
      __syncthreads();
      acc += t; hcnt[tid] = acc;
      __syncthreads();
    }
    bcur[b*NBK + tid] = acc - v;    // exclusive prefix
    return;
  }

  if (m == 3) {
    if (tid < 64) {
      const int c = tid;
      float wx = 0.f, wy = 0.f, wz = 0.f, be = bd2[c];
      for (int k = 0; k < 64; ++k) {
        float w = Wd2[c*64 + k];
        wx = fmaf(w, Wd1[k*3+0], wx);
        wy = fmaf(w, Wd1[k*3+1], wy);
        wz = fmaf(w, Wd1[k*3+2], wz);
        be = fmaf(w, bd1[k], be);
      }
      sWeff[c] = make_float4(wx, wy, wz, be);
    }
    __syncthreads();
    #pragma unroll
    for (int it = 0; it < 16; ++it) {
      const int e = it*256 + tid;  // e = o*64 + c
      const int o = e >> 6, c = e & 63;
      comb[c*CREC + 32 + o] = Wg[e];
    }
    if (tid < 64) {
      float4 wf = sWeff[tid];
      comb[tid*CREC+0] = wf.x; comb[tid*CREC+1] = wf.y;
      comb[tid*CREC+2] = wf.z; comb[tid*CREC+3] = wf.w;
    }
    return;
  }

  const int o = tid >> 2;
  const int q = tid & 3;

  const float* O  = (m == 2) ? Wal : Wg;
  const float* M  = (m == 0) ? Wphi : Wpsi;
  const float* bM = (m == 0) ? bphi : bpsi;

  if (m == 2) {
    for (int cc = 0; cc < 16; ++cc) sT[o*65 + q*16 + cc] = Wal[o*64 + q*16 + cc];
    if (q == 0) sTb[o] = bal[o];
  } else {
    float acc[16];
    #pragma unroll
    for (int cc = 0; cc < 16; ++cc) acc[cc] = 0.f;
    for (int k = 0; k < 64; ++k) {
      float w = O[o*64 + k];
      #pragma unroll
      for (int cc = 0; cc < 16; ++cc) acc[cc] = fmaf(w, M[k*64 + q*16 + cc], acc[cc]);
    }
    for (int cc = 0; cc < 16; ++cc) sT[o*65 + q*16 + cc] = acc[cc];
    if (q == 0) {
      float tb = (m == 0) ? bg[o] : 0.f;
      for (int k = 0; k < 64; ++k) tb = fmaf(O[o*64 + k], bM[k], tb);
      sTb[o] = tb;
    }
  }
  __syncthreads();

  float acc[16];
  #pragma unroll
  for (int cc = 0; cc < 16; ++cc) acc[cc] = 0.f;
  for (int k = 0; k < 64; ++k) {
    float w = sT[o*65 + k];
    #pragma unroll
    for (int cc = 0; cc < 16; ++cc) acc[cc] = fmaf(w, W1[k*64 + q*16 + cc], acc[cc]);
  }
  float* R  = (m == 0) ? Af  : (m == 1) ? Bf  : Cf;
  float* dR = (m == 0) ? dAv : (m == 1) ? dBv : dCv;
  for (int cc = 0; cc < 16; ++cc) R[o*64 + q*16 + cc] = acc[cc];
  if (q == 0) {
    float db = sTb[o];
    for (int k = 0; k < 64; ++k) db = fmaf(sT[o*65 + k], b1[k], db);
    dR[o] = db;
  }
}

// scatter + xyz passthrough (memcpy folded in)
__global__ void __launch_bounds__(256)
k_scatter(const float* __restrict__ xyz, const float4* __restrict__ brange,
          int* __restrict__ bcur, float4* __restrict__ spts, int* __restrict__ ssidx,
          int* __restrict__ rank, float* __restrict__ out_xyz)
{
  const int i = blockIdx.x * 256 + threadIdx.x;   // < NB*NP (global orig)
  const int b = i >> 13;
  const int orig = i & (NP - 1);
  const float x = xyz[(size_t)i*3+0];
  const float y = xyz[(size_t)i*3+1];
  const float z = xyz[(size_t)i*3+2];
  out_xyz[(size_t)i*3+0] = x;
  out_xyz[(size_t)i*3+1] = y;
  out_xyz[(size_t)i*3+2] = z;
  const float sq = __fadd_rn(__fadd_rn(__fmul_rn(x,x), __fmul_rn(y,y)), __fmul_rn(z,z));
  float4 br = brange[b];
  int k = min(max((int)((x - br.x) * br.y), 0), NBK - 1);
  int pos = atomicAdd(&bcur[b*NBK + k], 1);       // batch-local sorted position
  spts [(size_t)b * NP + pos] = make_float4(x, y, z, sq);
  ssidx[(size_t)b * NP + pos] = orig;
  rank [(size_t)b * NP + orig] = pos;
}

// ---------------- fused: KNN v9 (pipelined sweep) | wide-scalar GEMVs ----------
__global__ void __launch_bounds__(256)
k_knn_tf(const float4* __restrict__ spts, const int* __restrict__ ssidx,
         const float4* __restrict__ brange, int* __restrict__ knn_idx,
         const float* __restrict__ feat,
         const float* __restrict__ Af, const float* __restrict__ dAv,
         const float* __restrict__ Bf, const float* __restrict__ dBv,
         const float* __restrict__ Cf, const float* __restrict__ dCv,
         float* __restrict__ uA, float* __restrict__ uB, float* __restrict__ uC)
{
  const int tid = threadIdx.x;

  if (blockIdx.x >= KNN_BLOCKS) {
    // ---- transform: streaming x, dwordx16 weight loads ----
    const int tb    = blockIdx.x - KNN_BLOCKS;
    const int chunk = tb >> 6;                    // 0..11
    const int xblk  = tb & 63;
    const int m     = chunk >> 2;
    const int rb    = (chunk & 3) << 4;           // row base
    const float* __restrict__ M  = (m == 0) ? Af  : ((m == 1) ? Bf  : Cf);
    const float* __restrict__ dv = (m == 0) ? dAv : ((m == 1) ? dBv : dCv);
    float* __restrict__ O        = (m == 0) ? uA  : ((m == 1) ? uB  : uC);

    const size_t p = (size_t)xblk * 256 + tid;    // global sorted position
    const int b = (int)(p >> 13);
    const int orig = ssidx[p];                    // batch-local orig index
    const size_t frow = ((size_t)(b << 13) + orig) * D;
    const float4* xr = (const float4*)(feat + frow);

    float acc[16];
    #pragma unroll
    for (int r = 0; r < 16; ++r) acc[r] = dv[rb + r];

    #pragma unroll
    for (int c16 = 0; c16 < 4; ++c16) {
      float4 xa = xr[c16*4+0], xb = xr[c16*4+1], xc = xr[c16*4+2], xd = xr[c16*4+3];
      float xs[16] = {xa.x, xa.y, xa.z, xa.w, xb.x, xb.y, xb.z, xb.w,
                      xc.x, xc.y, xc.z, xc.w, xd.x, xd.y, xd.z, xd.w};
      #pragma unroll
      for (int r = 0; r < 16; ++r) {
        const f16v w = ((const f16v*)(M + (size_t)(rb + r) * D))[c16];  // s_load_dwordx16
        float a = acc[r];
        #pragma unroll
        for (int e = 0; e < 16; ++e) a = fmaf(w[e], xs[e], a);
        acc[r] = a;
      }
    }
    float4* op = (float4*)(O + p * D + rb);
    #pragma unroll
    for (int q = 0; q < 4; ++q)
      op[q] = make_float4(acc[q*4+0], acc[q*4+1], acc[q*4+2], acc[q*4+3]);
    return;
  }

  // ---- KNN v9: outward sweep with software-pipelined chunk loads ----
  const int qpos = (blockIdx.x * 256 + tid) >> 6;  // sorted position
  const int lane = tid & 63;
  const int b    = qpos >> 13;
  const int pos  = qpos & (NP - 1);
  const size_t bb = (size_t)b * NP;

  const float4 qp = spts[bb + pos];
  const float xi = qp.x, yi = qp.y, zi = qp.z, sqi = qp.w;
  const int si_q = ssidx[bb + pos];

  const float slack = __fmul_rn(brange[b].z, 1.01f);

  const int p0 = min(max(pos - 32, 0), NP - 64);

  unsigned kds, kidx;
  float thr_d2;

#define THR_REFRESH()                                                                    \
  {                                                                                      \
    float d16 = __uint_as_float((unsigned)__builtin_amdgcn_readlane((int)kds, KNN - 1)); \
    thr_d2 = __fmul_rn(__fmul_rn(d16, d16), 1.000001f);                                  \
  }

#define KPROCS(P, SIV, VALID)                                                            \
  {                                                                                      \
    float dot = __fadd_rn(__fadd_rn(__fmul_rn(xi,(P).x), __fmul_rn(yi,(P).y)),           \
                          __fmul_rn(zi,(P).z));                                          \
    float d2  = __fsub_rn(__fadd_rn(sqi, (P).w), __fmul_rn(2.0f, dot));                  \
    unsigned long long mask = __ballot((VALID) && d2 <= thr_d2);                         \
    if (mask) {                                                                          \
      float ds = __fsqrt_rn(fmaxf(d2, 0.0f));                                            \
      unsigned cds = __float_as_uint(ds);                                                \
      unsigned cidx = (unsigned)(SIV);                                                   \
      bool ins = false;                                                                  \
      do {                                                                               \
        const int src = __ffsll((long long)mask) - 1;                                    \
        mask &= mask - 1;                                                                \
        const unsigned ids  = (unsigned)__builtin_amdgcn_readlane((int)cds,  src);       \
        const unsigned iidx = (unsigned)__builtin_amdgcn_readlane((int)cidx, src);       \
        const bool less = (kds < ids) || ((kds == ids) && (kidx < iidx));                \
        const int pos2 = __popcll(__ballot((lane < KNN) && less));                       \
        if (pos2 < KNN) {                                                                \
          unsigned uds  = __shfl_up(kds,  1, 64);                                        \
          unsigned uidx = __shfl_up(kidx, 1, 64);                                        \
          if (lane < KNN) {                                                              \
            kds  = (lane < pos2) ? kds  : (lane == pos2 ? ids  : uds);                   \
            kidx = (lane < pos2) ? kidx : (lane == pos2 ? iidx : uidx);                  \
          }                                                                              \
          ins = true;                                                                    \
        }                                                                                \
      } while (mask);                                                                    \
      if (ins) THR_REFRESH()                                                             \
    }                                                                                    \
  }

  // init: bitonic top-16 over the 64-wide window around own sorted position
  {
    float4 P = spts[bb + p0 + lane];
    int SI = ssidx[bb + p0 + lane];
    float dot = __fadd_rn(__fadd_rn(__fmul_rn(xi,P.x), __fmul_rn(yi,P.y)), __fmul_rn(zi,P.z));
    float d2  = __fsub_rn(__fadd_rn(sqi, P.w), __fmul_rn(2.0f, dot));
    float ds  = __fsqrt_rn(fmaxf(d2, 0.0f));
    kds  = __float_as_uint(ds);
    kidx = (unsigned)SI;
  }
  #pragma unroll
  for (int k = 2; k <= 64; k <<= 1) {
    #pragma unroll
    for (int jj = k >> 1; jj >= 1; jj >>= 1) {
      unsigned ods  = __shfl_xor(kds,  jj, 64);
      unsigned oidx = __shfl_xor(kidx, jj, 64);
      const bool up    = (lane & k) == 0;
      const bool lower = (lane & jj) == 0;
      const bool takemin = (lower == up);
      const bool oless = (ods < kds) || ((ods == kds) && (oidx < kidx));
      const bool take = (takemin == oless);
      kds  = take ? ods  : kds;
      kidx = take ? oidx : kidx;
    }
  }
  if (lane >= KNN) { kds = 0x7F7FFFFFu; kidx = 0xFFFFu; }
  THR_REFRESH()

  // pipelined outward sweep: prefetch current chunks, then in-loop prefetch next
  int l = p0 - 1;                 // next-left position to scan (chunk = [baseL, l])
  int r = p0 + 64;                // next-right position (chunk = [r, r+63])
  bool goL = (l >= 0), goR = (r < NP);
  int baseL = max(l - 63, 0);

  float4 PL, PR; int SL = 0, SR = 0;
  if (goL) { PL = spts[bb + baseL + lane]; SL = ssidx[bb + baseL + lane]; }
  if (goR) { const int cl = min(r + lane, NP - 1); PR = spts[bb + cl]; SR = ssidx[bb + cl]; }

  #pragma unroll 1
  while (goL || goR) {
    // speculative next-chunk prefetch (issued before any dependent work)
    const int nl = baseL - 1;
    const int nbaseL = max(nl - 63, 0);
    const int nr = r + 64;
    const bool hasNL = goL && (nl >= 0);
    const bool hasNR = goR && (nr < NP);
    float4 nPL, nPR; int nSL = 0, nSR = 0;
    if (hasNL) { nPL = spts[bb + nbaseL + lane]; nSL = ssidx[bb + nbaseL + lane]; }
    if (hasNR) { const int cl = min(nr + lane, NP - 1); nPR = spts[bb + cl]; nSR = ssidx[bb + cl]; }

    if (goL) {
      const float xl = rl_f(PL.x, l - baseL);          // boundary element from prefetch
      const float gap = (xi - xl) - slack;
      if (gap > 0.f && __fmul_rn(gap, gap) > thr_d2 + 1e-3f) {
        goL = false;
      } else {
        const bool valid = (baseL + lane) <= l;
        KPROCS(PL, SL, valid)
        l = nl; baseL = nbaseL;
        PL = nPL; SL = nSL;
        goL = (l >= 0);
      }
    }
    if (goR) {
      const float xr = rl_f(PR.x, 0);                  // element at position r
      const float gap = (xr - xi) - slack;
      if (gap > 0.f && __fmul_rn(gap, gap) > thr_d2 + 1e-3f) {
        goR = false;
      } else {
        const bool valid = (r + lane) < NP;
        KPROCS(PR, SR, valid)
        r = nr;
        PR = nPR; SR = nSR;
        goR = (r < NP);
      }
    }
  }
#undef KPROCS
#undef THR_REFRESH

  if (lane < KNN) knn_idx[((size_t)b * NP + si_q) * KNN + lane] = (int)kidx;
}

// ---------------- main kernel v9: 5 waves/SIMD, uC prefetch, scalar weights ----
__global__ void __launch_bounds__(256, 5)
k_main9(const float4* __restrict__ spts, const int* __restrict__ ssidx,
        const int* __restrict__ rank,
        const float* __restrict__ feat,
        const int* __restrict__ knn_idx,
        const float* __restrict__ uA, const float* __restrict__ uB, const float* __restrict__ uC,
        const float* __restrict__ comb,
        const float* __restrict__ W2g, const float* __restrict__ b2g,
        float* __restrict__ out)
{
  __shared__ float sW2[64 * 68];
  __shared__ float sB2[64];
  __shared__ float sY[16 * 68];

  const int tid = threadIdx.x;
  {
    #pragma unroll
    for (int it = 0; it < 16; ++it) {
      const int e = it*256 + tid;
      sW2[(e >> 6)*68 + (e & 63)] = W2g[e];
    }
    if (tid < 64) sB2[tid] = b2g[tid];
  }
  __syncthreads();

  const int lane  = tid & 63;
  const int kslot = lane & 15;
  const int plocal = (tid >> 6) * 4 + (lane >> 4);
  const int p_s   = blockIdx.x * 16 + plocal;       // global sorted position
  const int b     = p_s >> 13;
  const size_t bb = (size_t)b * NP;

  const int orig_i = ssidx[p_s];                    // batch-local orig index
  const size_t orow = (bb + (size_t)orig_i) * D;    // feat/out row
  const size_t irow = (size_t)p_s * D;              // uA row (sorted)

  const int j = knn_idx[(bb + (size_t)orig_i) * KNN + kslot];  // batch-local orig j
  const int jpos = rank[bb + (size_t)j];                       // batch-local sorted pos
  const size_t jrow = (bb + (size_t)jpos) * D;                 // uB/uC row (sorted)

  const float4 pi = spts[p_s];
  const float4 pj = spts[bb + (size_t)jpos];
  const float dx = pi.x - pj.x;
  const float dy = pi.y - pj.y;
  const float dz = pi.z - pj.z;

  float gamma[64];
  {
    const float4* ua = (const float4*)(uA + irow);
    const float4* ub = (const float4*)(uB + jrow);
    #pragma unroll
    for (int cc = 0; cc < 16; ++cc) {
      float4 a = ua[cc];
      float4 v = ub[cc];
      gamma[cc*4+0] = a.x - v.x; gamma[cc*4+1] = a.y - v.y;
      gamma[cc*4+2] = a.z - v.z; gamma[cc*4+3] = a.w - v.w;
    }
  }

  #pragma unroll 4
  for (int c = 0; c < 64; ++c) {
    const float4 wf = *(const float4*)(comb + c*CREC);
    float t = fmaf(wf.z, dz, fmaf(wf.y, dy, fmaf(wf.x, dx, wf.w)));
    float d = fmaxf(t, 0.f);
    const f16v* wv = (const f16v*)(comb + c*CREC + 32);   // 64B-aligned -> dwordx16
    const f16v w0 = wv[0], w1 = wv[1], w2 = wv[2], w3 = wv[3];
    #pragma unroll
    for (int e = 0; e < 16; ++e) {
      gamma[e]      = fmaf(w0[e], d, gamma[e]);
      gamma[16 + e] = fmaf(w1[e], d, gamma[16 + e]);
      gamma[32 + e] = fmaf(w2[e], d, gamma[32 + e]);
      gamma[48 + e] = fmaf(w3[e], d, gamma[48 + e]);
    }
  }

  float m0 = gamma[0], m1 = gamma[1], m2 = gamma[2], m3 = gamma[3];
  #pragma unroll
  for (int c = 4; c < 64; c += 4) {
    m0 = fmaxf(m0, gamma[c+0]); m1 = fmaxf(m1, gamma[c+1]);
    m2 = fmaxf(m2, gamma[c+2]); m3 = fmaxf(m3, gamma[c+3]);
  }
  const float m = fmaxf(fmaxf(m0, m1), fmaxf(m2, m3));
  float s0 = 0.f, s1 = 0.f, s2 = 0.f, s3 = 0.f;
  #pragma unroll
  for (int c = 0; c < 64; c += 4) {
    gamma[c+0] = __expf(gamma[c+0] - m); s0 += gamma[c+0];
    gamma[c+1] = __expf(gamma[c+1] - m); s1 += gamma[c+1];
    gamma[c+2] = __expf(gamma[c+2] - m); s2 += gamma[c+2];
    gamma[c+3] = __expf(gamma[c+3] - m); s3 += gamma[c+3];
  }
  const float inv = 1.0f / ((s0 + s1) + (s2 + s3));

  {
    const float4* uc = (const float4*)(uC + jrow);
    float4 av = uc[0];                              // prefetch 1 ahead
    #pragma unroll
    for (int cc = 0; cc < 16; ++cc) {
      float4 avn;
      if (cc < 15) avn = uc[cc + 1];
      float avv[4] = {av.x, av.y, av.z, av.w};
      #pragma unroll
      for (int r = 0; r < 4; ++r) {
        const int c = cc*4 + r;
        const float4 wf = *(const float4*)(comb + c*CREC);
        float t = fmaf(wf.z, dz, fmaf(wf.y, dy, fmaf(wf.x, dx, wf.w)));
        float d = fmaxf(t, 0.f);
        gamma[c] = gamma[c] * inv * (avv[r] + d);
      }
      av = avn;
    }
  }

  // fold-tree reduce over the 16 kslot lanes
  float t8[32];
  {
    const bool hi = (kslot & 8) != 0;
    #pragma unroll
    for (int i2 = 0; i2 < 32; ++i2) {
      float sendv = hi ? gamma[i2] : gamma[i2+32];
      float keepv = hi ? gamma[i2+32] : gamma[i2];
      t8[i2] = keepv + __shfl_xor(sendv, 8, 64);
    }
  }
  float t4[16];
  {
    const bool hi = (kslot & 4) != 0;
    #pragma unroll
    for (int i2 = 0; i2 < 16; ++i2) {
      float sendv = hi ? t8[i2] : t8[i2+16];
      float keepv = hi ? t8[i2+16] : t8[i2];
      t4[i2] = keepv + __shfl_xor(sendv, 4, 64);
    }
  }
  float t2[8];
  {
    const bool hi = (kslot & 2) != 0;
    #pragma unroll
    for (int i2 = 0; i2 < 8; ++i2) {
      float sendv = hi ? t4[i2] : t4[i2+8];
      float keepv = hi ? t4[i2+8] : t4[i2];
      t2[i2] = keepv + __shfl_xor(sendv, 2, 64);
    }
  }
  float y0, y1, y2, y3;
  {
    const bool hi = (kslot & 1) != 0;
    float s0v = hi ? t2[0] : t2[4];
    float s1v = hi ? t2[1] : t2[5];
    float s2v = hi ? t2[2] : t2[6];
    float s3v = hi ? t2[3] : t2[7];
    float k0 = hi ? t2[4] : t2[0];
    float k1 = hi ? t2[5] : t2[1];
    float k2 = hi ? t2[6] : t2[2];
    float k3 = hi ? t2[7] : t2[3];
    y0 = k0 + __shfl_xor(s0v, 1, 64);
    y1 = k1 + __shfl_xor(s1v, 1, 64);
    y2 = k2 + __shfl_xor(s2v, 1, 64);
    y3 = k3 + __shfl_xor(s3v, 1, 64);
  }

  ((float4*)sY)[plocal * 17 + kslot] = make_float4(y0, y1, y2, y3);
  __syncthreads();
  float y[64];
  {
    const float4* yp = (const float4*)sY + plocal * 17;
    #pragma unroll
    for (int o4 = 0; o4 < 16; ++o4) {
      float4 v = yp[o4];
      y[o4*4+0] = v.x; y[o4*4+1] = v.y; y[o4*4+2] = v.z; y[o4*4+3] = v.w;
    }
  }

  const int oc = kslot * 4;
  float o0 = sB2[oc+0], o1 = sB2[oc+1], o2 = sB2[oc+2], o3 = sB2[oc+3];
  {
    const float4* r0 = (const float4*)(sW2 + (oc+0)*68);
    const float4* r1 = (const float4*)(sW2 + (oc+1)*68);
    const float4* r2 = (const float4*)(sW2 + (oc+2)*68);
    const float4* r3 = (const float4*)(sW2 + (oc+3)*68);
    #pragma unroll
    for (int c4 = 0; c4 < 16; ++c4) {
      float4 w0 = r0[c4], w1 = r1[c4], w2 = r2[c4], w3 = r3[c4];
      o0 = fmaf(w0.x, y[c4*4+0], o0); o0 = fmaf(w0.y, y[c4*4+1], o0);
      o0 = fmaf(w0.z, y[c4*4+2], o0); o0 = fmaf(w0.w, y[c4*4+3], o0);
      o1 = fmaf(w1.x, y[c4*4+0], o1); o1 = fmaf(w1.y, y[c4*4+1], o1);
      o1 = fmaf(w1.z, y[c4*4+2], o1); o1 = fmaf(w1.w, y[c4*4+3], o1);
      o2 = fmaf(w2.x, y[c4*4+0], o2); o2 = fmaf(w2.y, y[c4*4+1], o2);
      o2 = fmaf(w2.z, y[c4*4+2], o2); o2 = fmaf(w2.w, y[c4*4+3], o2);
      o3 = fmaf(w3.x, y[c4*4+0], o3); o3 = fmaf(w3.y, y[c4*4+1], o3);
      o3 = fmaf(w3.z, y[c4*4+2], o3); o3 = fmaf(w3.w, y[c4*4+3], o3);
    }
  }
  float4 fv = ((const float4*)(feat + orow))[kslot];
  ((float4*)(out + orow))[kslot] = make_float4(o0 + fv.x, o1 + fv.y, o2 + fv.z, o3 + fv.w);
}

extern "C" void kernel_launch(void* const* d_in, const int* in_sizes, int n_in,
                              void* d_out, int out_size, void* d_ws, size_t ws_size,
                              hipStream_t stream) {
  const float* xyz  = (const float*)d_in[0];
  const float* feat = (const float*)d_in[1];
  const float* W1   = (const float*)d_in[3];
  const float* b1   = (const float*)d_in[4];
  const float* Wphi = (const float*)d_in[5];
  const float* bphi = (const float*)d_in[6];
  const float* Wpsi = (const float*)d_in[7];
  const float* bpsi = (const float*)d_in[8];
  const float* Wal  = (const float*)d_in[9];
  const float* bal  = (const float*)d_in[10];
  const float* Wg   = (const float*)d_in[11];
  const float* bg   = (const float*)d_in[12];
  const float* Wd1  = (const float*)d_in[13];
  const float* bd1  = (const float*)d_in[14];
  const float* Wd2  = (const float*)d_in[15];
  const float* bd2  = (const float*)d_in[16];
  const float* W2   = (const float*)d_in[17];
  const float* b2   = (const float*)d_in[18];

  float* out = (float*)d_out;

  // workspace (f32 words): uA | uB | uC | knn_idx | folds | comb | bcur | brange | spts | ssidx | rank
  const size_t NPT = (size_t)NB * NP;     // 16384
  float* uA = (float*)d_ws;
  float* uB = uA + NPT * D;
  float* uC = uB + NPT * D;
  int* knn_idx = (int*)(uC + NPT * D);
  float* Af  = (float*)(knn_idx + NPT * KNN);
  float* dAv = Af + 4096;
  float* Bf  = dAv + 64;
  float* dBv = Bf + 4096;
  float* Cf  = dBv + 64;
  float* dCv = Cf + 4096;
  float* comb = dCv + 64;                 // 64*CREC floats (records 64B-aligned)
  int* bcur   = (int*)(comb + 64*CREC);   // NB*NBK
  float4* brange = (float4*)(bcur + NB*NBK);
  float4* spts   = brange + 4;            // NPT float4
  int* ssidx     = (int*)(spts + NPT);    // NPT ints
  int* rank      = ssidx + NPT;           // NPT ints

  k_foldbuckets<<<6, 256, 0, stream>>>(Wg, bg, Wphi, bphi, Wpsi, bpsi, Wal, bal, W1, b1,
                                       Wd1, bd1, Wd2, bd2, xyz,
                                       Af, dAv, Bf, dBv, Cf, dCv, comb, brange, bcur);
  k_scatter<<<NPT / 256, 256, 0, stream>>>(xyz, brange, bcur, spts, ssidx, rank, out);
  k_knn_tf<<<KNN_BLOCKS + 768, 256, 0, stream>>>(spts, ssidx, brange, knn_idx,
                                                 feat, Af, dAv, Bf, dBv, Cf, dCv,
                                                 uA, uB, uC);
  k_main9<<<NPT / 16, 256, 0, stream>>>(spts, ssidx, rank, feat, knn_idx,
                                        uA, uB, uC, comb, W2, b2, out + NPT * 3);
}

// Round 20
// 181.870 us; speedup vs baseline: 1.1404x; 1.1404x over previous
//
#include <hip/hip_runtime.h>

#define NB 2
#define NP 8192
#define D 64
#define KNN 16
#define NBK 256        // x-buckets per batch
#define KNN_BLOCKS (NB * NP / 4)   // 4096
#define CREC 96        // comb record stride (floats); W block at +32 (64B aligned)

typedef float f16v __attribute__((ext_vector_type(16)));

__device__ __forceinline__ float rl_f(float v, int lane) {
  return __uint_as_float((unsigned)__builtin_amdgcn_readlane((int)__float_as_uint(v), lane));
}

// ---------------- fused weight folding + bucket build (6 blocks) ----------------
__global__ void __launch_bounds__(256)
k_foldbuckets(const float* __restrict__ Wg,   const float* __restrict__ bg,
              const float* __restrict__ Wphi, const float* __restrict__ bphi,
              const float* __restrict__ Wpsi, const float* __restrict__ bpsi,
              const float* __restrict__ Wal,  const float* __restrict__ bal,
              const float* __restrict__ W1,   const float* __restrict__ b1,
              const float* __restrict__ Wd1,  const float* __restrict__ bd1,
              const float* __restrict__ Wd2,  const float* __restrict__ bd2,
              const float* __restrict__ xyz,
              float* __restrict__ Af, float* __restrict__ dAv,
              float* __restrict__ Bf, float* __restrict__ dBv,
              float* __restrict__ Cf, float* __restrict__ dCv,
              float* __restrict__ comb,
              float4* __restrict__ brange, int* __restrict__ bcur)
{
  __shared__ float sT[64 * 65];
  __shared__ float sTb[64];
  __shared__ float4 sWeff[64];
  __shared__ float smn[256], smx[256];
  __shared__ int hcnt[NBK];
  __shared__ float sr[2];
  const int m   = blockIdx.x;
  const int tid = threadIdx.x;

  if (m >= 4) {
    const int b = m - 4;
    float mn = 1e30f, mx = -1e30f;
    for (int i = tid; i < NP; i += 256) {
      float x = xyz[((size_t)b * NP + i) * 3];
      mn = fminf(mn, x); mx = fmaxf(mx, x);
    }
    smn[tid] = mn; smx[tid] = mx; __syncthreads();
    for (int off = 128; off >= 1; off >>= 1) {
      if (tid < off) {
        smn[tid] = fminf(smn[tid], smn[tid+off]);
        smx[tid] = fmaxf(smx[tid], smx[tid+off]);
      }
      __syncthreads();
    }
    if (tid == 0) {
      float xmin = smn[0], xmax = smx[0];
      float wdt = fmaxf((xmax - xmin) / (float)NBK, 1e-20f);
      brange[b] = make_float4(xmin, 1.0f / wdt, wdt, 0.f);
      sr[0] = xmin; sr[1] = 1.0f / wdt;
    }
    hcnt[tid] = 0;
    __syncthreads();

    const float xmin = sr[0], inv = sr[1];
    for (int i = tid; i < NP; i += 256) {
      float x = xyz[((size_t)b * NP + i) * 3];
      int k = min(max((int)((x - xmin) * inv), 0), NBK - 1);
      atomicAdd(&hcnt[k], 1);
    }
    __syncthreads();

    int v = hcnt[tid];
    int acc = v;
    for (int off = 1; off < NBK; off <<= 1) {
      int t = (tid >= off) ? hcnt[tid - off] : 0;
      __syncthreads();
      acc += t; hcnt[tid] = acc;
      __syncthreads();
    }
    bcur[b*NBK + tid] = acc - v;    // exclusive prefix
    return;
  }

  if (m == 3) {
    if (tid < 64) {
      const int c = tid;
      float wx = 0.f, wy = 0.f, wz = 0.f, be = bd2[c];
      for (int k = 0; k < 64; ++k) {
        float w = Wd2[c*64 + k];
        wx = fmaf(w, Wd1[k*3+0], wx);
        wy = fmaf(w, Wd1[k*3+1], wy);
        wz = fmaf(w, Wd1[k*3+2], wz);
        be = fmaf(w, bd1[k], be);
      }
      sWeff[c] = make_float4(wx, wy, wz, be);
    }
    __syncthreads();
    #pragma unroll
    for (int it = 0; it < 16; ++it) {
      const int e = it*256 + tid;  // e = o*64 + c
      const int o = e >> 6, c = e & 63;
      comb[c*CREC + 32 + o] = Wg[e];
    }
    if (tid < 64) {
      float4 wf = sWeff[tid];
      comb[tid*CREC+0] = wf.x; comb[tid*CREC+1] = wf.y;
      comb[tid*CREC+2] = wf.z; comb[tid*CREC+3] = wf.w;
    }
    return;
  }

  const int o = tid >> 2;
  const int q = tid & 3;

  const float* O  = (m == 2) ? Wal : Wg;
  const float* M  = (m == 0) ? Wphi : Wpsi;
  const float* bM = (m == 0) ? bphi : bpsi;

  if (m == 2) {
    for (int cc = 0; cc < 16; ++cc) sT[o*65 + q*16 + cc] = Wal[o*64 + q*16 + cc];
    if (q == 0) sTb[o] = bal[o];
  } else {
    float acc[16];
    #pragma unroll
    for (int cc = 0; cc < 16; ++cc) acc[cc] = 0.f;
    for (int k = 0; k < 64; ++k) {
      float w = O[o*64 + k];
      #pragma unroll
      for (int cc = 0; cc < 16; ++cc) acc[cc] = fmaf(w, M[k*64 + q*16 + cc], acc[cc]);
    }
    for (int cc = 0; cc < 16; ++cc) sT[o*65 + q*16 + cc] = acc[cc];
    if (q == 0) {
      float tb = (m == 0) ? bg[o] : 0.f;
      for (int k = 0; k < 64; ++k) tb = fmaf(O[o*64 + k], bM[k], tb);
      sTb[o] = tb;
    }
  }
  __syncthreads();

  float acc[16];
  #pragma unroll
  for (int cc = 0; cc < 16; ++cc) acc[cc] = 0.f;
  for (int k = 0; k < 64; ++k) {
    float w = sT[o*65 + k];
    #pragma unroll
    for (int cc = 0; cc < 16; ++cc) acc[cc] = fmaf(w, W1[k*64 + q*16 + cc], acc[cc]);
  }
  float* R  = (m == 0) ? Af  : (m == 1) ? Bf  : Cf;
  float* dR = (m == 0) ? dAv : (m == 1) ? dBv : dCv;
  for (int cc = 0; cc < 16; ++cc) R[o*64 + q*16 + cc] = acc[cc];
  if (q == 0) {
    float db = sTb[o];
    for (int k = 0; k < 64; ++k) db = fmaf(sT[o*65 + k], b1[k], db);
    dR[o] = db;
  }
}

// scatter + xyz passthrough (memcpy folded in)
__global__ void __launch_bounds__(256)
k_scatter(const float* __restrict__ xyz, const float4* __restrict__ brange,
          int* __restrict__ bcur, float4* __restrict__ spts, int* __restrict__ ssidx,
          int* __restrict__ rank, float* __restrict__ out_xyz)
{
  const int i = blockIdx.x * 256 + threadIdx.x;   // < NB*NP (global orig)
  const int b = i >> 13;
  const int orig = i & (NP - 1);
  const float x = xyz[(size_t)i*3+0];
  const float y = xyz[(size_t)i*3+1];
  const float z = xyz[(size_t)i*3+2];
  out_xyz[(size_t)i*3+0] = x;
  out_xyz[(size_t)i*3+1] = y;
  out_xyz[(size_t)i*3+2] = z;
  const float sq = __fadd_rn(__fadd_rn(__fmul_rn(x,x), __fmul_rn(y,y)), __fmul_rn(z,z));
  float4 br = brange[b];
  int k = min(max((int)((x - br.x) * br.y), 0), NBK - 1);
  int pos = atomicAdd(&bcur[b*NBK + k], 1);       // batch-local sorted position
  spts [(size_t)b * NP + pos] = make_float4(x, y, z, sq);
  ssidx[(size_t)b * NP + pos] = orig;
  rank [(size_t)b * NP + orig] = pos;
}

// ---------------- fused: KNN v9 (pipelined sweep) | wide-scalar GEMVs ----------
__global__ void __launch_bounds__(256)
k_knn_tf(const float4* __restrict__ spts, const int* __restrict__ ssidx,
         const float4* __restrict__ brange, int* __restrict__ knn_idx,
         const float* __restrict__ feat,
         const float* __restrict__ Af, const float* __restrict__ dAv,
         const float* __restrict__ Bf, const float* __restrict__ dBv,
         const float* __restrict__ Cf, const float* __restrict__ dCv,
         float* __restrict__ uA, float* __restrict__ uB, float* __restrict__ uC)
{
  const int tid = threadIdx.x;

  if (blockIdx.x >= KNN_BLOCKS) {
    // ---- transform: streaming x, dwordx16 weight loads ----
    const int tb    = blockIdx.x - KNN_BLOCKS;
    const int chunk = tb >> 6;                    // 0..11
    const int xblk  = tb & 63;
    const int m     = chunk >> 2;
    const int rb    = (chunk & 3) << 4;           // row base
    const float* __restrict__ M  = (m == 0) ? Af  : ((m == 1) ? Bf  : Cf);
    const float* __restrict__ dv = (m == 0) ? dAv : ((m == 1) ? dBv : dCv);
    float* __restrict__ O        = (m == 0) ? uA  : ((m == 1) ? uB  : uC);

    const size_t p = (size_t)xblk * 256 + tid;    // global sorted position
    const int b = (int)(p >> 13);
    const int orig = ssidx[p];                    // batch-local orig index
    const size_t frow = ((size_t)(b << 13) + orig) * D;
    const float4* xr = (const float4*)(feat + frow);

    float acc[16];
    #pragma unroll
    for (int r = 0; r < 16; ++r) acc[r] = dv[rb + r];

    #pragma unroll
    for (int c16 = 0; c16 < 4; ++c16) {
      float4 xa = xr[c16*4+0], xb = xr[c16*4+1], xc = xr[c16*4+2], xd = xr[c16*4+3];
      float xs[16] = {xa.x, xa.y, xa.z, xa.w, xb.x, xb.y, xb.z, xb.w,
                      xc.x, xc.y, xc.z, xc.w, xd.x, xd.y, xd.z, xd.w};
      #pragma unroll
      for (int r = 0; r < 16; ++r) {
        const f16v w = ((const f16v*)(M + (size_t)(rb + r) * D))[c16];  // s_load_dwordx16
        float a = acc[r];
        #pragma unroll
        for (int e = 0; e < 16; ++e) a = fmaf(w[e], xs[e], a);
        acc[r] = a;
      }
    }
    float4* op = (float4*)(O + p * D + rb);
    #pragma unroll
    for (int q = 0; q < 4; ++q)
      op[q] = make_float4(acc[q*4+0], acc[q*4+1], acc[q*4+2], acc[q*4+3]);
    return;
  }

  // ---- KNN v9: outward sweep with software-pipelined chunk loads ----
  const int qpos = (blockIdx.x * 256 + tid) >> 6;  // sorted position
  const int lane = tid & 63;
  const int b    = qpos >> 13;
  const int pos  = qpos & (NP - 1);
  const size_t bb = (size_t)b * NP;

  const float4 qp = spts[bb + pos];
  const float xi = qp.x, yi = qp.y, zi = qp.z, sqi = qp.w;
  const int si_q = ssidx[bb + pos];

  const float slack = __fmul_rn(brange[b].z, 1.01f);

  const int p0 = min(max(pos - 32, 0), NP - 64);

  unsigned kds, kidx;
  float thr_d2;

#define THR_REFRESH()                                                                    \
  {                                                                                      \
    float d16 = __uint_as_float((unsigned)__builtin_amdgcn_readlane((int)kds, KNN - 1)); \
    thr_d2 = __fmul_rn(__fmul_rn(d16, d16), 1.000001f);                                  \
  }

#define KPROCS(P, SIV, VALID)                                                            \
  {                                                                                      \
    float dot = __fadd_rn(__fadd_rn(__fmul_rn(xi,(P).x), __fmul_rn(yi,(P).y)),           \
                          __fmul_rn(zi,(P).z));                                          \
    float d2  = __fsub_rn(__fadd_rn(sqi, (P).w), __fmul_rn(2.0f, dot));                  \
    unsigned long long mask = __ballot((VALID) && d2 <= thr_d2);                         \
    if (mask) {                                                                          \
      float ds = __fsqrt_rn(fmaxf(d2, 0.0f));                                            \
      unsigned cds = __float_as_uint(ds);                                                \
      unsigned cidx = (unsigned)(SIV);                                                   \
      bool ins = false;                                                                  \
      do {                                                                               \
        const int src = __ffsll((long long)mask) - 1;                                    \
        mask &= mask - 1;                                                                \
        const unsigned ids  = (unsigned)__builtin_amdgcn_readlane((int)cds,  src);       \
        const unsigned iidx = (unsigned)__builtin_amdgcn_readlane((int)cidx, src);       \
        const bool less = (kds < ids) || ((kds == ids) && (kidx < iidx));                \
        const int pos2 = __popcll(__ballot((lane < KNN) && less));                       \
        if (pos2 < KNN) {                                                                \
          unsigned uds  = __shfl_up(kds,  1, 64);                                        \
          unsigned uidx = __shfl_up(kidx, 1, 64);                                        \
          if (lane < KNN) {                                                              \
            kds  = (lane < pos2) ? kds  : (lane == pos2 ? ids  : uds);                   \
            kidx = (lane < pos2) ? kidx : (lane == pos2 ? iidx : uidx);                  \
          }                                                                              \
          ins = true;                                                                    \
        }                                                                                \
      } while (mask);                                                                    \
      if (ins) THR_REFRESH()                                                             \
    }                                                                                    \
  }

  // init: bitonic top-16 over the 64-wide window around own sorted position
  {
    float4 P = spts[bb + p0 + lane];
    int SI = ssidx[bb + p0 + lane];
    float dot = __fadd_rn(__fadd_rn(__fmul_rn(xi,P.x), __fmul_rn(yi,P.y)), __fmul_rn(zi,P.z));
    float d2  = __fsub_rn(__fadd_rn(sqi, P.w), __fmul_rn(2.0f, dot));
    float ds  = __fsqrt_rn(fmaxf(d2, 0.0f));
    kds  = __float_as_uint(ds);
    kidx = (unsigned)SI;
  }
  #pragma unroll
  for (int k = 2; k <= 64; k <<= 1) {
    #pragma unroll
    for (int jj = k >> 1; jj >= 1; jj >>= 1) {
      unsigned ods  = __shfl_xor(kds,  jj, 64);
      unsigned oidx = __shfl_xor(kidx, jj, 64);
      const bool up    = (lane & k) == 0;
      const bool lower = (lane & jj) == 0;
      const bool takemin = (lower == up);
      const bool oless = (ods < kds) || ((ods == kds) && (oidx < kidx));
      const bool take = (takemin == oless);
      kds  = take ? ods  : kds;
      kidx = take ? oidx : kidx;
    }
  }
  if (lane >= KNN) { kds = 0x7F7FFFFFu; kidx = 0xFFFFu; }
  THR_REFRESH()

  // pipelined outward sweep: prefetch current chunks, then in-loop prefetch next
  int l = p0 - 1;                 // next-left position to scan (chunk = [baseL, l])
  int r = p0 + 64;                // next-right position (chunk = [r, r+63])
  bool goL = (l >= 0), goR = (r < NP);
  int baseL = max(l - 63, 0);

  float4 PL, PR; int SL = 0, SR = 0;
  if (goL) { PL = spts[bb + baseL + lane]; SL = ssidx[bb + baseL + lane]; }
  if (goR) { const int cl = min(r + lane, NP - 1); PR = spts[bb + cl]; SR = ssidx[bb + cl]; }

  #pragma unroll 1
  while (goL || goR) {
    // speculative next-chunk prefetch (issued before any dependent work)
    const int nl = baseL - 1;
    const int nbaseL = max(nl - 63, 0);
    const int nr = r + 64;
    const bool hasNL = goL && (nl >= 0);
    const bool hasNR = goR && (nr < NP);
    float4 nPL, nPR; int nSL = 0, nSR = 0;
    if (hasNL) { nPL = spts[bb + nbaseL + lane]; nSL = ssidx[bb + nbaseL + lane]; }
    if (hasNR) { const int cl = min(nr + lane, NP - 1); nPR = spts[bb + cl]; nSR = ssidx[bb + cl]; }

    if (goL) {
      const float xl = rl_f(PL.x, l - baseL);          // boundary element from prefetch
      const float gap = (xi - xl) - slack;
      if (gap > 0.f && __fmul_rn(gap, gap) > thr_d2 + 1e-3f) {
        goL = false;
      } else {
        const bool valid = (baseL + lane) <= l;
        KPROCS(PL, SL, valid)
        l = nl; baseL = nbaseL;
        PL = nPL; SL = nSL;
        goL = (l >= 0);
      }
    }
    if (goR) {
      const float xr = rl_f(PR.x, 0);                  // element at position r
      const float gap = (xr - xi) - slack;
      if (gap > 0.f && __fmul_rn(gap, gap) > thr_d2 + 1e-3f) {
        goR = false;
      } else {
        const bool valid = (r + lane) < NP;
        KPROCS(PR, SR, valid)
        r = nr;
        PR = nPR; SR = nSR;
        goR = (r < NP);
      }
    }
  }
#undef KPROCS
#undef THR_REFRESH

  if (lane < KNN) knn_idx[((size_t)b * NP + si_q) * KNN + lane] = (int)kidx;
}

// ---------------- main kernel v8: sorted-space gathers, dwordx16 scalar weights ----
__global__ void __launch_bounds__(256, 4)
k_main8(const float4* __restrict__ spts, const int* __restrict__ ssidx,
        const int* __restrict__ rank,
        const float* __restrict__ feat,
        const int* __restrict__ knn_idx,
        const float* __restrict__ uA, const float* __restrict__ uB, const float* __restrict__ uC,
        const float* __restrict__ comb,
        const float* __restrict__ W2g, const float* __restrict__ b2g,
        float* __restrict__ out)
{
  __shared__ float sW2[64 * 68];
  __shared__ float sB2[64];
  __shared__ float sY[16 * 68];

  const int tid = threadIdx.x;
  {
    #pragma unroll
    for (int it = 0; it < 16; ++it) {
      const int e = it*256 + tid;
      sW2[(e >> 6)*68 + (e & 63)] = W2g[e];
    }
    if (tid < 64) sB2[tid] = b2g[tid];
  }
  __syncthreads();

  const int lane  = tid & 63;
  const int kslot = lane & 15;
  const int plocal = (tid >> 6) * 4 + (lane >> 4);
  const int p_s   = blockIdx.x * 16 + plocal;       // global sorted position
  const int b     = p_s >> 13;
  const size_t bb = (size_t)b * NP;

  const int orig_i = ssidx[p_s];                    // batch-local orig index
  const size_t orow = (bb + (size_t)orig_i) * D;    // feat/out row
  const size_t irow = (size_t)p_s * D;              // uA row (sorted)

  const int j = knn_idx[(bb + (size_t)orig_i) * KNN + kslot];  // batch-local orig j
  const int jpos = rank[bb + (size_t)j];                       // batch-local sorted pos
  const size_t jrow = (bb + (size_t)jpos) * D;                 // uB/uC row (sorted)

  const float4 pi = spts[p_s];
  const float4 pj = spts[bb + (size_t)jpos];
  const float dx = pi.x - pj.x;
  const float dy = pi.y - pj.y;
  const float dz = pi.z - pj.z;

  float gamma[64];
  {
    const float4* ua = (const float4*)(uA + irow);
    const float4* ub = (const float4*)(uB + jrow);
    #pragma unroll
    for (int cc = 0; cc < 16; ++cc) {
      float4 a = ua[cc];
      float4 v = ub[cc];
      gamma[cc*4+0] = a.x - v.x; gamma[cc*4+1] = a.y - v.y;
      gamma[cc*4+2] = a.z - v.z; gamma[cc*4+3] = a.w - v.w;
    }
  }

  #pragma unroll 4
  for (int c = 0; c < 64; ++c) {
    const float4 wf = *(const float4*)(comb + c*CREC);
    float t = fmaf(wf.z, dz, fmaf(wf.y, dy, fmaf(wf.x, dx, wf.w)));
    float d = fmaxf(t, 0.f);
    const f16v* wv = (const f16v*)(comb + c*CREC + 32);   // 64B-aligned -> dwordx16
    const f16v w0 = wv[0], w1 = wv[1], w2 = wv[2], w3 = wv[3];
    #pragma unroll
    for (int e = 0; e < 16; ++e) {
      gamma[e]      = fmaf(w0[e], d, gamma[e]);
      gamma[16 + e] = fmaf(w1[e], d, gamma[16 + e]);
      gamma[32 + e] = fmaf(w2[e], d, gamma[32 + e]);
      gamma[48 + e] = fmaf(w3[e], d, gamma[48 + e]);
    }
  }

  float m0 = gamma[0], m1 = gamma[1], m2 = gamma[2], m3 = gamma[3];
  #pragma unroll
  for (int c = 4; c < 64; c += 4) {
    m0 = fmaxf(m0, gamma[c+0]); m1 = fmaxf(m1, gamma[c+1]);
    m2 = fmaxf(m2, gamma[c+2]); m3 = fmaxf(m3, gamma[c+3]);
  }
  const float m = fmaxf(fmaxf(m0, m1), fmaxf(m2, m3));
  float s0 = 0.f, s1 = 0.f, s2 = 0.f, s3 = 0.f;
  #pragma unroll
  for (int c = 0; c < 64; c += 4) {
    gamma[c+0] = __expf(gamma[c+0] - m); s0 += gamma[c+0];
    gamma[c+1] = __expf(gamma[c+1] - m); s1 += gamma[c+1];
    gamma[c+2] = __expf(gamma[c+2] - m); s2 += gamma[c+2];
    gamma[c+3] = __expf(gamma[c+3] - m); s3 += gamma[c+3];
  }
  const float inv = 1.0f / ((s0 + s1) + (s2 + s3));

  {
    const float4* uc = (const float4*)(uC + jrow);
    #pragma unroll
    for (int cc = 0; cc < 16; ++cc) {
      float4 av = uc[cc];
      float avv[4] = {av.x, av.y, av.z, av.w};
      #pragma unroll
      for (int r = 0; r < 4; ++r) {
        const int c = cc*4 + r;
        const float4 wf = *(const float4*)(comb + c*CREC);
        float t = fmaf(wf.z, dz, fmaf(wf.y, dy, fmaf(wf.x, dx, wf.w)));
        float d = fmaxf(t, 0.f);
        gamma[c] = gamma[c] * inv * (avv[r] + d);
      }
    }
  }

  // fold-tree reduce over the 16 kslot lanes
  float t8[32];
  {
    const bool hi = (kslot & 8) != 0;
    #pragma unroll
    for (int i2 = 0; i2 < 32; ++i2) {
      float sendv = hi ? gamma[i2] : gamma[i2+32];
      float keepv = hi ? gamma[i2+32] : gamma[i2];
      t8[i2] = keepv + __shfl_xor(sendv, 8, 64);
    }
  }
  float t4[16];
  {
    const bool hi = (kslot & 4) != 0;
    #pragma unroll
    for (int i2 = 0; i2 < 16; ++i2) {
      float sendv = hi ? t8[i2] : t8[i2+16];
      float keepv = hi ? t8[i2+16] : t8[i2];
      t4[i2] = keepv + __shfl_xor(sendv, 4, 64);
    }
  }
  float t2[8];
  {
    const bool hi = (kslot & 2) != 0;
    #pragma unroll
    for (int i2 = 0; i2 < 8; ++i2) {
      float sendv = hi ? t4[i2] : t4[i2+8];
      float keepv = hi ? t4[i2+8] : t4[i2];
      t2[i2] = keepv + __shfl_xor(sendv, 2, 64);
    }
  }
  float y0, y1, y2, y3;
  {
    const bool hi = (kslot & 1) != 0;
    float s0v = hi ? t2[0] : t2[4];
    float s1v = hi ? t2[1] : t2[5];
    float s2v = hi ? t2[2] : t2[6];
    float s3v = hi ? t2[3] : t2[7];
    float k0 = hi ? t2[4] : t2[0];
    float k1 = hi ? t2[5] : t2[1];
    float k2 = hi ? t2[6] : t2[2];
    float k3 = hi ? t2[7] : t2[3];
    y0 = k0 + __shfl_xor(s0v, 1, 64);
    y1 = k1 + __shfl_xor(s1v, 1, 64);
    y2 = k2 + __shfl_xor(s2v, 1, 64);
    y3 = k3 + __shfl_xor(s3v, 1, 64);
  }

  ((float4*)sY)[plocal * 17 + kslot] = make_float4(y0, y1, y2, y3);
  __syncthreads();
  float y[64];
  {
    const float4* yp = (const float4*)sY + plocal * 17;
    #pragma unroll
    for (int o4 = 0; o4 < 16; ++o4) {
      float4 v = yp[o4];
      y[o4*4+0] = v.x; y[o4*4+1] = v.y; y[o4*4+2] = v.z; y[o4*4+3] = v.w;
    }
  }

  const int oc = kslot * 4;
  float o0 = sB2[oc+0], o1 = sB2[oc+1], o2 = sB2[oc+2], o3 = sB2[oc+3];
  {
    const float4* r0 = (const float4*)(sW2 + (oc+0)*68);
    const float4* r1 = (const float4*)(sW2 + (oc+1)*68);
    const float4* r2 = (const float4*)(sW2 + (oc+2)*68);
    const float4* r3 = (const float4*)(sW2 + (oc+3)*68);
    #pragma unroll
    for (int c4 = 0; c4 < 16; ++c4) {
      float4 w0 = r0[c4], w1 = r1[c4], w2 = r2[c4], w3 = r3[c4];
      o0 = fmaf(w0.x, y[c4*4+0], o0); o0 = fmaf(w0.y, y[c4*4+1], o0);
      o0 = fmaf(w0.z, y[c4*4+2], o0); o0 = fmaf(w0.w, y[c4*4+3], o0);
      o1 = fmaf(w1.x, y[c4*4+0], o1); o1 = fmaf(w1.y, y[c4*4+1], o1);
      o1 = fmaf(w1.z, y[c4*4+2], o1); o1 = fmaf(w1.w, y[c4*4+3], o1);
      o2 = fmaf(w2.x, y[c4*4+0], o2); o2 = fmaf(w2.y, y[c4*4+1], o2);
      o2 = fmaf(w2.z, y[c4*4+2], o2); o2 = fmaf(w2.w, y[c4*4+3], o2);
      o3 = fmaf(w3.x, y[c4*4+0], o3); o3 = fmaf(w3.y, y[c4*4+1], o3);
      o3 = fmaf(w3.z, y[c4*4+2], o3); o3 = fmaf(w3.w, y[c4*4+3], o3);
    }
  }
  float4 fv = ((const float4*)(feat + orow))[kslot];
  ((float4*)(out + orow))[kslot] = make_float4(o0 + fv.x, o1 + fv.y, o2 + fv.z, o3 + fv.w);
}

extern "C" void kernel_launch(void* const* d_in, const int* in_sizes, int n_in,
                              void* d_out, int out_size, void* d_ws, size_t ws_size,
                              hipStream_t stream) {
  const float* xyz  = (const float*)d_in[0];
  const float* feat = (const float*)d_in[1];
  const float* W1   = (const float*)d_in[3];
  const float* b1   = (const float*)d_in[4];
  const float* Wphi = (const float*)d_in[5];
  const float* bphi = (const float*)d_in[6];
  const float* Wpsi = (const float*)d_in[7];
  const float* bpsi = (const float*)d_in[8];
  const float* Wal  = (const float*)d_in[9];
  const float* bal  = (const float*)d_in[10];
  const float* Wg   = (const float*)d_in[11];
  const float* bg   = (const float*)d_in[12];
  const float* Wd1  = (const float*)d_in[13];
  const float* bd1  = (const float*)d_in[14];
  const float* Wd2  = (const float*)d_in[15];
  const float* bd2  = (const float*)d_in[16];
  const float* W2   = (const float*)d_in[17];
  const float* b2   = (const float*)d_in[18];

  float* out = (float*)d_out;

  // workspace (f32 words): uA | uB | uC | knn_idx | folds | comb | bcur | brange | spts | ssidx | rank
  const size_t NPT = (size_t)NB * NP;     // 16384
  float* uA = (float*)d_ws;
  float* uB = uA + NPT * D;
  float* uC = uB + NPT * D;
  int* knn_idx = (int*)(uC + NPT * D);
  float* Af  = (float*)(knn_idx + NPT * KNN);
  float* dAv = Af + 4096;
  float* Bf  = dAv + 64;
  float* dBv = Bf + 4096;
  float* Cf  = dBv + 64;
  float* dCv = Cf + 4096;
  float* comb = dCv + 64;                 // 64*CREC floats (records 64B-aligned)
  int* bcur   = (int*)(comb + 64*CREC);   // NB*NBK
  float4* brange = (float4*)(bcur + NB*NBK);
  float4* spts   = brange + 4;            // NPT float4
  int* ssidx     = (int*)(spts + NPT);    // NPT ints
  int* rank      = ssidx + NPT;           // NPT ints

  k_foldbuckets<<<6, 256, 0, stream>>>(Wg, bg, Wphi, bphi, Wpsi, bpsi, Wal, bal, W1, b1,
                                       Wd1, bd1, Wd2, bd2, xyz,
                                       Af, dAv, Bf, dBv, Cf, dCv, comb, brange, bcur);
  k_scatter<<<NPT / 256, 256, 0, stream>>>(xyz, brange, bcur, spts, ssidx, rank, out);
  k_knn_tf<<<KNN_BLOCKS + 768, 256, 0, stream>>>(spts, ssidx, brange, knn_idx,
                                                 feat, Af, dAv, Bf, dBv, Cf, dCv,
                                                 uA, uB, uC);
  k_main8<<<NPT / 16, 256, 0, stream>>>(spts, ssidx, rank, feat, knn_idx,
                                        uA, uB, uC, comb, W2, b2, out + NPT * 3);
}